// Round 1
// baseline (461.896 us; speedup 1.0000x reference)
//
#include <hip/hip_runtime.h>

#define BATCH  8
#define NSMALL 12288
#define NFULL  24576
#define CCH    256
#define KSTEP  4096
#define JCH    4   // j-chunks of 1024
#define KBLK   4   // k-blocks of 1024

// Step k (processed order) corresponds to original column c = KSTEP-1-k:
//   f_k = order[b][0][c], t_k = order[b][1][c]
// Step semantics: vf[t_k] = vf[f_k]  (read-before-write within a step)

// Phase 1: for each k, partial results over a j-chunk:
//   bestJ = max{ j in chunk : j < k && t_j == f_k }   (last prior writer of f_k)
//   later = exists j in chunk : j > k && t_j == t_k    (k is NOT last writer of t_k)
__global__ __launch_bounds__(1024) void k_scan(const int* __restrict__ order,
                                               int* __restrict__ pb,
                                               int* __restrict__ pl) {
    const int b  = blockIdx.x;
    const int kb = blockIdx.y;
    const int jc = blockIdx.z;
    __shared__ int tl[1024];

    const int* ob = order + b * 2 * KSTEP;
    const int j0 = jc * 1024;
    // load t values for this j-chunk (processed order)
    tl[threadIdx.x] = ob[KSTEP + (KSTEP - 1 - (j0 + threadIdx.x))];
    __syncthreads();

    const int k  = kb * 1024 + threadIdx.x;
    const int fk = ob[(KSTEP - 1 - k)];
    const int tk = ob[KSTEP + (KSTEP - 1 - k)];

    int bestJ = -1;
    int later = 0;
#pragma unroll 8
    for (int jj = 0; jj < 1024; ++jj) {
        const int j  = j0 + jj;
        const int tv = tl[jj];
        if (tv == fk && j < k) bestJ = j;   // j increasing -> keeps max
        later |= (tv == tk && j > k);
    }
    const int idx = ((b * JCH + jc) * KSTEP) + k;
    pb[idx] = bestJ;
    pl[idx] = later;
}

// Phase 2: combine partials, pointer-jump to roots, scatter last-writers,
// then map root row -> image position via binary search over mask_idx.
__global__ __launch_bounds__(1024) void k_resolve(const int* __restrict__ order,
                                                  const int* __restrict__ mask_idx,
                                                  const int* __restrict__ pb,
                                                  const int* __restrict__ pl,
                                                  int* __restrict__ gmap) {
    const int b = blockIdx.x;
    __shared__ int p0[KSTEP], p1[KSTEP], v0[KSTEP], v1[KSTEP], lastf[KSTEP];
    const int* ob = order + b * 2 * KSTEP;

    for (int kk = 0; kk < 4; ++kk) {
        const int k = kk * 1024 + threadIdx.x;
        int bj = -1, lat = 0;
        for (int jc = 0; jc < JCH; ++jc) {
            const int idx = ((b * JCH + jc) * KSTEP) + k;
            const int v = pb[idx];
            if (v > bj) bj = v;
            lat |= pl[idx];
        }
        p0[k] = bj;                      // J(k) or -1
        v0[k] = ob[KSTEP - 1 - k];       // f_k (root candidate)
        lastf[k] = !lat;                 // k is last writer of t_k
    }
    __syncthreads();

    // Wyllie pointer jumping: invariant: p==-1 => v == final root row
    int* pc = p0; int* pn = p1; int* vc = v0; int* vn = v1;
    for (int r = 0; r < 12; ++r) {
        for (int kk = 0; kk < 4; ++kk) {
            const int k = kk * 1024 + threadIdx.x;
            const int j = pc[k];
            if (j < 0) { pn[k] = -1;    vn[k] = vc[k]; }
            else       { pn[k] = pc[j]; vn[k] = vc[j]; }
        }
        __syncthreads();
        int* t;
        t = pc; pc = pn; pn = t;
        t = vc; vc = vn; vn = t;
    }

    // identity init, then scatter resolved roots for last-writers
    int* gb = gmap + b * NFULL;
    for (int n = threadIdx.x; n < NFULL; n += 1024) gb[n] = n;
    __syncthreads();
    for (int kk = 0; kk < 4; ++kk) {
        const int k = kk * 1024 + threadIdx.x;
        if (lastf[k]) gb[ob[KSTEP + (KSTEP - 1 - k)]] = vc[k];
    }
    __syncthreads();

    // root row -> image position (or -1 => zero row)
    const int* mb = mask_idx + b * NSMALL;
    for (int n = threadIdx.x; n < NFULL; n += 1024) {
        const int root = gb[n];
        int lo = 0, hi = NSMALL - 1, pos = -1;
        while (lo <= hi) {
            const int mid = (lo + hi) >> 1;
            const int mv = mb[mid];
            if (mv == root) { pos = mid; break; }
            if (mv < root) lo = mid + 1; else hi = mid - 1;
        }
        gb[n] = pos;
    }
}

// Phase 3: gather rows. One wave per output row, one float4 per lane.
__global__ __launch_bounds__(256) void k_copy(const float4* __restrict__ img,
                                              const int* __restrict__ gmap,
                                              float4* __restrict__ out) {
    const int r    = blockIdx.x * 4 + (threadIdx.x >> 6);
    const int lane = threadIdx.x & 63;
    const int g = gmap[r];
    const int b = r / NFULL;
    float4* o = out + (size_t)r * 64 + lane;
    if (g < 0) {
        *o = make_float4(0.f, 0.f, 0.f, 0.f);
    } else {
        *o = img[((size_t)(b * NSMALL + g)) * 64 + lane];
    }
}

extern "C" void kernel_launch(void* const* d_in, const int* in_sizes, int n_in,
                              void* d_out, int out_size, void* d_ws, size_t ws_size,
                              hipStream_t stream) {
    const float* images  = (const float*)d_in[0];
    const int* mask_idx  = (const int*)d_in[1];
    const int* order     = (const int*)d_in[2];
    float* out           = (float*)d_out;

    int* ws   = (int*)d_ws;
    int* pb   = ws;                                // BATCH*JCH*KSTEP ints
    int* pl   = pb + BATCH * JCH * KSTEP;          // BATCH*JCH*KSTEP ints
    int* gmap = pl + BATCH * JCH * KSTEP;          // BATCH*NFULL ints

    k_scan<<<dim3(BATCH, KBLK, JCH), 1024, 0, stream>>>(order, pb, pl);
    k_resolve<<<dim3(BATCH), 1024, 0, stream>>>(order, mask_idx, pb, pl, gmap);
    k_copy<<<dim3(BATCH * NFULL / 4), 256, 0, stream>>>((const float4*)images, gmap,
                                                        (float4*)out);
}

// Round 2
// 302.597 us; speedup vs baseline: 1.5264x; 1.5264x over previous
//
#include <hip/hip_runtime.h>

#define BATCH  8
#define NSMALL 12288
#define NFULL  24576
#define KSTEP  4096
#define JCHUNK 512   // j-tile staged in LDS
#define KCHUNK 256   // k per block (= block size)

// Step k (processed order) = original column c = KSTEP-1-k:
//   f_k = order[b][0][c], t_k = order[b][1][c];  semantics: vf[t_k] = vf[f_k]
// Row value provenance: root(k) = f_j of the start of the chain
//   k -> J(k) -> J(J(k)) ... where J(k) = max{ j < k : t_j == f_k }.
// Final row n = last writer's root (packed atomicMax, key = step index).

// Init: gmap = packed identity ((k=0)<<15 | n), inv = -1, p = -1
__global__ __launch_bounds__(256) void k_init(int* __restrict__ gmap,
                                              int* __restrict__ inv,
                                              int* __restrict__ p) {
    const int tid = blockIdx.x * 256 + threadIdx.x;       // B*NFULL threads
    gmap[tid] = tid % NFULL;
    inv[tid]  = -1;
    if (tid < BATCH * KSTEP) p[tid] = -1;
}

// inv[b][row] = image position
__global__ __launch_bounds__(256) void k_inv(const int* __restrict__ mask_idx,
                                             int* __restrict__ inv) {
    const int tid = blockIdx.x * 256 + threadIdx.x;       // B*NSMALL threads
    const int b = tid / NSMALL, i = tid % NSMALL;
    inv[b * NFULL + mask_idx[tid]] = i;
}

// p[b][k] = J(k) via chunked O(K^2) max-match; atomicMax-combined across j-chunks
__global__ __launch_bounds__(256) void k_scan(const int* __restrict__ order,
                                              int* __restrict__ p) {
    const int b  = blockIdx.x;
    const int k0 = blockIdx.y * KCHUNK;
    const int j0 = blockIdx.z * JCHUNK;
    if (j0 >= k0 + KCHUNK) return;                        // whole chunk has j >= k

    __shared__ alignas(16) int tl[JCHUNK];
    const int* ob = order + b * 2 * KSTEP;
    for (int i = threadIdx.x; i < JCHUNK; i += 256)
        tl[i] = ob[2 * KSTEP - 1 - (j0 + i)];             // t_j for j in chunk
    __syncthreads();

    const int k  = k0 + threadIdx.x;
    const int fk = ob[KSTEP - 1 - k];
    int best = -1;

    if (j0 + JCHUNK <= k0) {                              // all j < k: no bound check
        const int4* tl4 = (const int4*)tl;
#pragma unroll 4
        for (int q = 0; q < JCHUNK / 4; ++q) {
            const int4 tv = tl4[q];
            if (tv.x == fk) best = 4 * q;
            if (tv.y == fk) best = 4 * q + 1;
            if (tv.z == fk) best = 4 * q + 2;
            if (tv.w == fk) best = 4 * q + 3;
        }
    } else {                                              // diagonal: per-lane bound
        int jmax = k - j0;
        if (jmax > JCHUNK) jmax = JCHUNK;
        for (int jj = 0; jj < jmax; ++jj)
            if (tl[jj] == fk) best = jj;
    }
    if (best >= 0) atomicMax(&p[b * KSTEP + k], j0 + best);
}

// Chase chain to root row; scatter packed (k+1)<<15 | root, last writer wins.
__global__ __launch_bounds__(256) void k_chase(const int* __restrict__ order,
                                               const int* __restrict__ p,
                                               int* __restrict__ gmap) {
    const int tid = blockIdx.x * 256 + threadIdx.x;       // B*KSTEP threads
    const int b = tid / KSTEP, k = tid % KSTEP;
    const int* ob = order + b * 2 * KSTEP;
    const int* pb = p + b * KSTEP;
    int j = k, pj;
    while ((pj = pb[j]) >= 0) j = pj;                     // J strictly decreasing
    const int root = ob[KSTEP - 1 - j];
    const int t    = ob[2 * KSTEP - 1 - k];
    atomicMax(&gmap[b * NFULL + t], ((k + 1) << 15) | root);
}

// One wave per 256-float row; root -> image pos via inv; zero if absent.
__global__ __launch_bounds__(256) void k_copy(const float4* __restrict__ img,
                                              const int* __restrict__ gmap,
                                              const int* __restrict__ inv,
                                              float4* __restrict__ out) {
    const int r    = blockIdx.x * 4 + (threadIdx.x >> 6);
    const int lane = threadIdx.x & 63;
    const int b    = r / NFULL;
    const int root = gmap[r] & 0x7fff;
    const int pos  = inv[b * NFULL + root];
    float4* o = out + (size_t)r * 64 + lane;
    if (pos < 0) *o = make_float4(0.f, 0.f, 0.f, 0.f);
    else         *o = img[((size_t)b * NSMALL + pos) * 64 + lane];
}

extern "C" void kernel_launch(void* const* d_in, const int* in_sizes, int n_in,
                              void* d_out, int out_size, void* d_ws, size_t ws_size,
                              hipStream_t stream) {
    const float* images = (const float*)d_in[0];
    const int* mask_idx = (const int*)d_in[1];
    const int* order    = (const int*)d_in[2];
    float* out          = (float*)d_out;

    int* ws   = (int*)d_ws;
    int* p    = ws;                          // B*KSTEP
    int* gmap = p + BATCH * KSTEP;           // B*NFULL
    int* inv  = gmap + BATCH * NFULL;        // B*NFULL

    k_init <<<BATCH * NFULL / 256, 256, 0, stream>>>(gmap, inv, p);
    k_inv  <<<BATCH * NSMALL / 256, 256, 0, stream>>>(mask_idx, inv);
    k_scan <<<dim3(BATCH, KSTEP / KCHUNK, KSTEP / JCHUNK), 256, 0, stream>>>(order, p);
    k_chase<<<BATCH * KSTEP / 256, 256, 0, stream>>>(order, p, gmap);
    k_copy <<<BATCH * NFULL / 4, 256, 0, stream>>>((const float4*)images, gmap,
                                                   inv, (float4*)out);
}